// Round 4
// baseline (154.173 us; speedup 1.0000x reference)
//
#include <hip/hip_runtime.h>
#include <hip/hip_fp16.h>

// fePAM: per-pixel gather attention. Shapes fixed by setup_inputs().
constexpr int B = 2, C = 64, H = 128, W = 256, N = H * W, K = 32;

typedef _Float16 hf2 __attribute__((ext_vector_type(2)));

// DPP helper (VALU-pipe cross-lane; keeps softmax off the LDS pipe)
template <int CTRL>
__device__ __forceinline__ float dppf(float x) {
    int i = __builtin_bit_cast(int, x);
    int r = __builtin_amdgcn_update_dpp(i, i, CTRL, 0xF, 0xF, false);
    return __builtin_bit_cast(float, r);
}

// ---------------------------------------------------------------------------
// Transpose+downconvert [B][C][N] fp32 -> [B][N][C] fp16 for S, R, AND Q.
// grid = (N/64, B, 3), block = 256.  (z: 0=S, 1=R, 2=Q)
// ---------------------------------------------------------------------------
__global__ __launch_bounds__(256) void transpose_to_h(
    const float* __restrict__ Q, const float* __restrict__ S,
    const float* __restrict__ R,
    __half* __restrict__ Qt, __half* __restrict__ St, __half* __restrict__ Rt) {
    __shared__ float tile[C][65];  // 2-way bank aliasing only (free)
    const int n0 = blockIdx.x * 64;
    const int b  = blockIdx.y;
    const int z  = blockIdx.z;
    const float* src = (z == 0 ? S : (z == 1 ? R : Q)) + (size_t)b * C * N;
    __half2* d2 = (__half2*)((z == 0 ? St : (z == 1 ? Rt : Qt)) +
                             (size_t)b * N * C);
    {
        const int j = threadIdx.x & 63, c0 = threadIdx.x >> 6;
        const float* s = src + n0 + j;
#pragma unroll
        for (int r = 0; r < 16; ++r) {
            int c = c0 + r * 4;
            tile[c][j] = s[(size_t)c * N];  // coalesced 256B along n
        }
    }
    __syncthreads();
    {
        const int c2 = threadIdx.x & 31, j0 = threadIdx.x >> 5;  // j0 0..7
#pragma unroll
        for (int r = 0; r < 8; ++r) {
            int j = j0 + 8 * r;
            d2[(size_t)(n0 + j) * 32 + c2] =  // 256B contiguous per wave
                __floats2half2_rn(tile[2 * c2][j], tile[2 * c2 + 1][j]);
        }
    }
}

// ---------------------------------------------------------------------------
// Attention: one wave per pixel-octet, block = 8 waves = 64-pixel tile.
// grid = (N/64 * B), block = 512. Phase-split: scores for all 8 pixels, then
// values for all 8 pixels (separates St vs Rt working sets in L2).
// ---------------------------------------------------------------------------
__global__ __launch_bounds__(512, 8) void fepam_attn(
    const __half* __restrict__ Qt,
    const int* __restrict__ Px, const int* __restrict__ Py,
    const __half* __restrict__ St, const __half* __restrict__ Rt,
    float* __restrict__ Out) {
    __shared__ __align__(16) float ot[64][66];          // 16.9 KB
    __shared__ __align__(16) unsigned aidx[8][8][32];   //  8.0 KB

    const int tid  = threadIdx.x;
    const int lane = tid & 63;
    const int wave = tid >> 6;   // 0..7
    const int bx   = blockIdx.x;
    // XCD batch-parity swizzle: keep each XCD's L2 on one batch's planes.
    const int b    = bx & 1;
    const int n0   = (bx >> 1) * 64;

    const __half* Qtb = Qt + (size_t)b * N * C;
    const __half* Stb = St + (size_t)b * N * C;
    const __half* Rtb = Rt + (size_t)b * N * C;

    // ================= phase 1: scores + softmax for the wave's 8 pixels ===
    const int k = lane & 31;  // candidate this lane owns
    const int h = lane >> 5;  // which 64B half of the key/query vector
#pragma unroll 2
    for (int p = 0; p < 8; ++p) {
        const int n = n0 + wave * 8 + p;

        const int px  = Px[(size_t)n * K + k];
        const int py  = Py[(size_t)n * K + k];
        const int idx = px * W + py;

        const float4* kp = (const float4*)(Stb + (size_t)idx * C + h * 32);
        const float4* qp = (const float4*)(Qtb + (size_t)n * C + h * 32);
        float s = 0.f;
#pragma unroll
        for (int i = 0; i < 4; ++i) {
            float4 kraw = kp[i];   // 8 halves of the key
            float4 qraw = qp[i];   // 8 halves of q (L1 broadcast hit)
            const hf2* k2 = (const hf2*)&kraw;
            const hf2* q2 = (const hf2*)&qraw;
#pragma unroll
            for (int u = 0; u < 4; ++u)
                s = __builtin_amdgcn_fdot2(k2[u], q2[u], s, false);
        }
        s += __shfl_xor(s, 32);  // combine the two c-halves

        // softmax over 32 candidates: 4 DPP stages (VALU) + 1 xor16 shfl
        float m = s;
        m = fmaxf(m, dppf<0xB1>(m));    // quad_perm [1,0,3,2]  (xor1)
        m = fmaxf(m, dppf<0x4E>(m));    // quad_perm [2,3,0,1]  (xor2)
        m = fmaxf(m, dppf<0x141>(m));   // row_half_mirror      (8-group)
        m = fmaxf(m, dppf<0x140>(m));   // row_mirror           (16-group)
        m = fmaxf(m, __shfl_xor(m, 16));
        float e = __expf(s - m);
        float l = e;
        l += dppf<0xB1>(l);
        l += dppf<0x4E>(l);
        l += dppf<0x141>(l);
        l += dppf<0x140>(l);
        l += __shfl_xor(l, 16);
        const float a = e / l;

        // publish packed (idx, fp16 attn): idx < 32768 fits 15 bits
        if (lane < 32)
            aidx[wave][p][k] = ((unsigned)idx << 16) |
                               (unsigned)__half_as_ushort(__float2half_rn(a));
    }
    // aidx is produced and consumed by the SAME wave -> no barrier needed.

    // ================= phase 2: attention-weighted value sums ==============
    const int c2 = lane & 31;  // c-pair this lane owns
    const int kh = lane >> 5;  // k-subparity (2 value rows per instr)
    for (int p = 0; p < 8; ++p) {
        const int j = wave * 8 + p;
        float accx = 0.f, accy = 0.f;
#pragma unroll
        for (int g = 0; g < 8; ++g) {  // 4 candidates per b128 broadcast read
            const uint4 pk4 = *(const uint4*)&aidx[wave][p][4 * g];
            const unsigned ua = kh ? pk4.z : pk4.x;  // k = 4g + 2*kh
            const unsigned ub = kh ? pk4.w : pk4.y;  // k = 4g + 2*kh + 1
#pragma unroll
            for (int t = 0; t < 2; ++t) {
                const unsigned u = t ? ub : ua;
                const float a = __half2float(__ushort_as_half((unsigned short)(u & 0xffffu)));
                const __half2 v =
                    *(const __half2*)(Rtb + ((size_t)(u >> 16) << 6) + 2 * c2);
                const float2 vf = __half22float2(v);
                accx = fmaf(a, vf.x, accx);
                accy = fmaf(a, vf.y, accy);
            }
        }
        accx += __shfl_xor(accx, 32);  // combine the two k-subparities
        accy += __shfl_xor(accy, 32);
        if (lane < 32)
            *(float2*)&ot[j][2 * c2] = make_float2(accx, accy);
    }
    __syncthreads();

    // ---- store: ot[j][c] -> Out[b][c][n0+j] (coalesced 256B along n)
    {
        const int j = tid & 63, c0 = tid >> 6;
        float* od = Out + (size_t)b * C * N + n0 + j;
#pragma unroll
        for (int r = 0; r < 8; ++r) {
            int c = c0 + r * 8;
            od[(size_t)c * N] = ot[j][c];
        }
    }
}

// ---------------------------------------------------------------------------
extern "C" void kernel_launch(void* const* d_in, const int* in_sizes, int n_in,
                              void* d_out, int out_size, void* d_ws, size_t ws_size,
                              hipStream_t stream) {
    const float* Q  = (const float*)d_in[0];
    const float* S  = (const float*)d_in[1];
    const float* R  = (const float*)d_in[2];
    const int*   Px = (const int*)d_in[3];
    const int*   Py = (const int*)d_in[4];
    float* Out = (float*)d_out;

    // workspace: St, Rt, Qt fp16 (4.19 MB each)
    __half* St = (__half*)d_ws;
    __half* Rt = St + (size_t)B * N * C;
    __half* Qt = Rt + (size_t)B * N * C;

    dim3 tgrid(N / 64, B, 3);
    transpose_to_h<<<tgrid, 256, 0, stream>>>(Q, S, R, Qt, St, Rt);

    dim3 agrid(N / 64 * B);
    fepam_attn<<<agrid, 512, 0, stream>>>(Qt, Px, Py, St, Rt, Out);
}